// Round 2
// baseline (62.205 us; speedup 1.0000x reference)
//
#include <hip/hip_runtime.h>

#define ALPHA 0.05f

// B=32, H=512, W=512 hardcoded: all addressing is shifts/masks.
// Each thread processes 4 consecutive pixels in x (one float4 of I1).
__global__ __launch_bounds__(256) void dataterm_kernel(
    const float* __restrict__ I1,
    const float* __restrict__ I2,
    const float* __restrict__ flow,
    float* __restrict__ out)
{
    constexpr int W = 512, H = 512;

    int c = blockIdx.x * blockDim.x + threadIdx.x;   // chunk id: 4 pixels
    int x0c = (c & 127) << 2;                        // 0,4,...,508
    int y   = (c >> 7) & 511;
    int b   = c >> 16;

    int base = b << 18;                              // b*H*W
    int pix  = base + (y << 9) + x0c;

    // I1 row y: 4 pixels, plus the x+4 neighbor for the last pixel's dx
    float4 i1v = *reinterpret_cast<const float4*>(I1 + pix);
    float  i1n = (x0c + 4 < W) ? I1[pix + 4] : 0.0f;
    // I1 row y+1 (for the reference's mislabeled "grad_x" == dy). If y==H-1,
    // reuse row y so the difference is exactly 0.
    float4 i1d = (y < H - 1) ? *reinterpret_cast<const float4*>(I1 + pix + W) : i1v;

    // flow: 2 floats per pixel -> 8 floats = two float4 (32B-aligned: pix%4==0)
    const float4* fl = reinterpret_cast<const float4*>(flow + 2 * pix);
    float4 fA = fl[0];   // u0 v0 u1 v1
    float4 fB = fl[1];   // u2 v2 u3 v3

    float i1[4]  = { i1v.x, i1v.y, i1v.z, i1v.w };
    float i1r[4] = { i1v.y, i1v.z, i1v.w, i1n };    // right neighbor
    float i1b[4] = { i1d.x, i1d.y, i1d.z, i1d.w };  // below neighbor
    float u[4] = { fA.x, fA.z, fB.x, fB.z };
    float v[4] = { fA.y, fA.w, fB.y, fB.w };

    const float* I2b = I2 + base;
    float un[4], vn[4];

#pragma unroll
    for (int i = 0; i < 4; ++i) {
        int x = x0c + i;
        // reference naming swap: "grad_x" is the VERTICAL diff (dy),
        // "grad_y" is the HORIZONTAL diff (dx)
        float g_dy = i1b[i] - i1[i];                          // 0 at y==H-1 by construction
        float g_dx = (x < W - 1) ? (i1r[i] - i1[i]) : 0.0f;

        float xx = fminf(fmaxf((float)x + u[i], 0.0f), (float)(W - 1));
        float yy = fminf(fmaxf((float)y + v[i], 0.0f), (float)(H - 1));
        float x0f = floorf(xx);
        float y0f = floorf(yy);
        int x0 = (int)x0f;
        int y0 = (int)y0f;
        int x1 = min(x0 + 1, W - 1);
        int y1 = min(y0 + 1, H - 1);
        float wx = xx - x0f;
        float wy = yy - y0f;

        int r0 = y0 << 9;
        int r1 = y1 << 9;
        float Ia = I2b[r0 + x0];
        float Ib = I2b[r0 + x1];
        float Ic = I2b[r1 + x0];
        float Id = I2b[r1 + x1];
        float top = Ia + wx * (Ib - Ia);
        float bot = Ic + wx * (Id - Ic);
        float warped = top + wy * (bot - top);

        float dataTerm = warped - i1[i];
        un[i] = u[i] - ALPHA * dataTerm * g_dy;
        vn[i] = v[i] - ALPHA * dataTerm * g_dx;
    }

    float4* op = reinterpret_cast<float4*>(out + 2 * pix);
    op[0] = make_float4(un[0], vn[0], un[1], vn[1]);
    op[1] = make_float4(un[2], vn[2], un[3], vn[3]);
}

extern "C" void kernel_launch(void* const* d_in, const int* in_sizes, int n_in,
                              void* d_out, int out_size, void* d_ws, size_t ws_size,
                              hipStream_t stream) {
    const float* I1   = (const float*)d_in[0];
    const float* I2   = (const float*)d_in[1];
    const float* flow = (const float*)d_in[2];
    float* out = (float*)d_out;

    const int B = 32, H = 512, W = 512;
    const int chunks = B * H * W / 4;   // 2,097,152 threads

    int block = 256;
    int grid = chunks / block;
    dataterm_kernel<<<grid, block, 0, stream>>>(I1, I2, flow, out);
}

// Round 4
// 60.773 us; speedup vs baseline: 1.0236x; 1.0236x over previous
//
#include <hip/hip_runtime.h>

#define ALPHA 0.05f

typedef float f32x4 __attribute__((ext_vector_type(4)));
typedef float f32x2 __attribute__((ext_vector_type(2)));

// B=32, H=512, W=512 hardcoded. 2 pixels per thread:
//  - flow load  = one float4/lane (16B, lane-contiguous, nontemporal)
//  - out store  = one float4/lane (16B, lane-contiguous, nontemporal)
//  - I1 loads   = float2/lane (8B, lane-contiguous)
//  - 8 scalar gathers (2 independent bilinear chains per thread)
__global__ __launch_bounds__(256) void dataterm_kernel(
    const float* __restrict__ I1,
    const float* __restrict__ I2,
    const float* __restrict__ flow,
    float* __restrict__ out)
{
    constexpr int W = 512, H = 512;

    int c   = blockIdx.x * 256 + threadIdx.x;   // chunk id: 2 pixels
    int x0c = (c & 255) << 1;                   // 0,2,...,510
    int y   = (c >> 8) & 511;
    int b   = c >> 17;

    int base = b << 18;                         // b*H*W
    int pix  = base + (y << 9) + x0c;

    f32x2 i1v = *reinterpret_cast<const f32x2*>(I1 + pix);
    // right neighbor of pixel x0c+1 (only needed when x0c+1 < W-1)
    float i1n = (x0c < W - 2) ? I1[pix + 2] : 0.0f;
    // row below (reference's mislabeled "grad_x" == vertical diff); at the
    // last row reuse row y so the diff is exactly 0.
    f32x2 i1d = (y < H - 1) ? *reinterpret_cast<const f32x2*>(I1 + pix + W) : i1v;

    // flow for both pixels: u0 v0 u1 v1 — streamed once, bypass L2
    f32x4 fA = __builtin_nontemporal_load(
        reinterpret_cast<const f32x4*>(flow + 2 * pix));

    float i1[2]  = { i1v.x, i1v.y };
    float i1r[2] = { i1v.y, i1n  };
    float i1b[2] = { i1d.x, i1d.y };
    float u[2]   = { fA.x, fA.z };
    float v[2]   = { fA.y, fA.w };

    const float* I2b = I2 + base;
    float un[2], vn[2];

#pragma unroll
    for (int i = 0; i < 2; ++i) {
        int x = x0c + i;
        // reference naming swap: "grad_x" = vertical diff, "grad_y" = horizontal
        float g_dy = i1b[i] - i1[i];
        float g_dx = (x < W - 1) ? (i1r[i] - i1[i]) : 0.0f;

        float xx = fminf(fmaxf((float)x + u[i], 0.0f), (float)(W - 1));
        float yy = fminf(fmaxf((float)y + v[i], 0.0f), (float)(H - 1));
        float x0f = floorf(xx);
        float y0f = floorf(yy);
        int x0 = (int)x0f;
        int y0 = (int)y0f;
        int x1 = min(x0 + 1, W - 1);
        int y1 = min(y0 + 1, H - 1);
        float wx = xx - x0f;
        float wy = yy - y0f;

        int r0 = y0 << 9;
        int r1 = y1 << 9;
        float Ia = I2b[r0 + x0];
        float Ib = I2b[r0 + x1];
        float Ic = I2b[r1 + x0];
        float Id = I2b[r1 + x1];
        float top = Ia + wx * (Ib - Ia);
        float bot = Ic + wx * (Id - Ic);
        float warped = top + wy * (bot - top);

        float dataTerm = warped - i1[i];
        un[i] = u[i] - ALPHA * dataTerm * g_dy;
        vn[i] = v[i] - ALPHA * dataTerm * g_dx;
    }

    // one fully-coalesced 16B store; touch-once stream, bypass L2
    f32x4 ov;
    ov.x = un[0]; ov.y = vn[0]; ov.z = un[1]; ov.w = vn[1];
    __builtin_nontemporal_store(ov, reinterpret_cast<f32x4*>(out + 2 * pix));
}

extern "C" void kernel_launch(void* const* d_in, const int* in_sizes, int n_in,
                              void* d_out, int out_size, void* d_ws, size_t ws_size,
                              hipStream_t stream) {
    const float* I1   = (const float*)d_in[0];
    const float* I2   = (const float*)d_in[1];
    const float* flow = (const float*)d_in[2];
    float* out = (float*)d_out;

    const int B = 32, H = 512, W = 512;
    const int chunks = B * H * W / 2;   // 4,194,304 threads

    int block = 256;
    int grid = chunks / block;          // 16384 blocks
    dataterm_kernel<<<grid, block, 0, stream>>>(I1, I2, flow, out);
}

// Round 5
// 50.693 us; speedup vs baseline: 1.2271x; 1.1989x over previous
//
#include <hip/hip_runtime.h>

#define ALPHA 0.05f

typedef float f32x2 __attribute__((ext_vector_type(2)));

// Tile 64 wide x 32 tall. Halo 8 each side (+1 col/row for the x1/y1 tap).
// Staged I2 region: 81 cols x 49 rows, border-clamped (duplicated) so the
// bilinear lookup needs no per-tap clamping.
constexpr int TXB = 64, TYB = 32;
constexpr int HALO = 8;
constexpr int RW = TXB + 2 * HALO + 1;   // 81
constexpr int RH = TYB + 2 * HALO + 1;   // 49
constexpr int LDS_N = RW * RH;           // 3969 floats = 15.9 KB

__global__ __launch_bounds__(256) void dataterm_kernel(
    const float* __restrict__ I1,
    const float* __restrict__ I2,
    const float* __restrict__ flow,
    float* __restrict__ out)
{
    __shared__ float s_i2[LDS_N];

    int blk = blockIdx.x;
    int tx0 = (blk & 7) << 6;            // 8 x-tiles
    int ty0 = ((blk >> 3) & 15) << 5;    // 16 y-tiles
    int b   = blk >> 7;                  // 32 images
    int base = b << 18;

    const float* I2b = I2 + base;
    const float* I1b = I1 + base;

    // ---- stage clamped 81x49 I2 region (coalesced scalar loads) ----
    int tid = threadIdx.x;
    for (int i = tid; i < LDS_N; i += 256) {
        int r = i / RW;                  // const-div -> mul/shift
        int c = i - r * RW;
        int sy = min(max(ty0 - HALO + r, 0), 511);
        int sx = min(max(tx0 - HALO + c, 0), 511);
        s_i2[i] = I2b[(sy << 9) + sx];
    }
    __syncthreads();

    // ---- compute: 8 pixels/thread, lanes cover consecutive x ----
    int xl = tid & 63;
    int x  = tx0 + xl;
    int yw = tid >> 6;                   // 0..3

    for (int j = 0; j < 8; ++j) {
        int y   = ty0 + yw + (j << 2);
        int pix = (y << 9) + x;

        f32x2 uv = __builtin_nontemporal_load(
            reinterpret_cast<const f32x2*>(flow + 2 * (base + pix)));
        float u = uv.x, v = uv.y;

        float i1 = I1b[pix];
        // reference naming swap: "grad_x" = vertical diff, "grad_y" = horizontal
        float g_dy = (y < 511) ? (I1b[pix + 512] - i1) : 0.0f;
        float g_dx = (x < 511) ? (I1b[pix + 1] - i1) : 0.0f;

        float xx = fminf(fmaxf((float)x + u, 0.0f), 511.0f);
        float yy = fminf(fmaxf((float)y + v, 0.0f), 511.0f);
        float x0f = floorf(xx);
        float y0f = floorf(yy);
        int x0 = (int)x0f;
        int y0 = (int)y0f;
        float wx = xx - x0f;
        float wy = yy - y0f;

        float Ia, Ib_, Ic, Id;
        bool oob = fmaxf(fabsf(u), fabsf(v)) > 8.0f;
        if (__builtin_expect(!oob, 1)) {
            // in-halo: provably 0 <= lx0,ly0 <= 79 and +1 stays <= 80
            int lidx = (y0 - ty0 + HALO) * RW + (x0 - tx0 + HALO);
            Ia  = s_i2[lidx];
            Ib_ = s_i2[lidx + 1];
            Ic  = s_i2[lidx + RW];
            Id  = s_i2[lidx + RW + 1];
        } else {
            // rare fallback: exact reference path from global
            int x1 = min(x0 + 1, 511);
            int y1 = min(y0 + 1, 511);
            Ia  = I2b[(y0 << 9) + x0];
            Ib_ = I2b[(y0 << 9) + x1];
            Ic  = I2b[(y1 << 9) + x0];
            Id  = I2b[(y1 << 9) + x1];
        }

        float top = Ia + wx * (Ib_ - Ia);
        float bot = Ic + wx * (Id - Ic);
        float warped = top + wy * (bot - top);

        float dt = warped - i1;
        f32x2 o;
        o.x = u - ALPHA * dt * g_dy;
        o.y = v - ALPHA * dt * g_dx;
        __builtin_nontemporal_store(o,
            reinterpret_cast<f32x2*>(out + 2 * (base + pix)));
    }
}

extern "C" void kernel_launch(void* const* d_in, const int* in_sizes, int n_in,
                              void* d_out, int out_size, void* d_ws, size_t ws_size,
                              hipStream_t stream) {
    const float* I1   = (const float*)d_in[0];
    const float* I2   = (const float*)d_in[1];
    const float* flow = (const float*)d_in[2];
    float* out = (float*)d_out;

    // 32 images x (8 x-tiles) x (16 y-tiles) = 4096 blocks
    dataterm_kernel<<<4096, 256, 0, stream>>>(I1, I2, flow, out);
}

// Round 6
// 43.468 us; speedup vs baseline: 1.4311x; 1.1662x over previous
//
#include <hip/hip_runtime.h>

#define ALPHA 0.05f

typedef float f32x4 __attribute__((ext_vector_type(4)));
typedef float f32x2 __attribute__((ext_vector_type(2)));

// Tile 64 wide x 32 tall. Halo 8 each side; staged I2 region 84 cols x 49
// rows (84 = 16B-aligned round-up of 81), border-clamped (duplicated), so
// in-halo bilinear taps need no clamping.
constexpr int RW = 84, RH = 49;
constexpr int CH4 = RW / 4;              // 21 float4-chunks per row
constexpr int LDS_N = RW * RH;           // 4116 floats = 16.5 KB

__global__ __launch_bounds__(256) void dataterm_kernel(
    const float* __restrict__ I1,
    const float* __restrict__ I2,
    const float* __restrict__ flow,
    float* __restrict__ out)
{
    __shared__ float s_i2[LDS_N];

    int blk = blockIdx.x;
    int tx0 = (blk & 7) << 6;            // 8 x-tiles
    int ty0 = ((blk >> 3) & 15) << 5;    // 16 y-tiles
    int b   = blk >> 7;                  // 32 images
    int base = b << 18;

    const float* I2b = I2 + base;
    const float* I1b = I1 + base;
    int tid = threadIdx.x;

    // ---- stage clamped 84x49 I2 region ----
    if (tx0 >= 64 && tx0 <= 384) {
        // x-interior: columns tx0-8 .. tx0+75 all in-range, 16B-aligned
        const float* src = I2b + tx0 - 8;
        for (int i = tid; i < CH4 * RH; i += 256) {
            int r  = i / CH4;
            int c4 = (i - r * CH4) << 2;
            int sy = min(max(ty0 - 8 + r, 0), 511);
            *reinterpret_cast<f32x4*>(&s_i2[r * RW + c4]) =
                *reinterpret_cast<const f32x4*>(src + (sy << 9) + c4);
        }
    } else {
        // edge tiles: scalar with per-element clamp (duplicated border)
        for (int i = tid; i < LDS_N; i += 256) {
            int r = i / RW;
            int c = i - r * RW;
            int sy = min(max(ty0 - 8 + r, 0), 511);
            int sx = min(max(tx0 - 8 + c, 0), 511);
            s_i2[i] = I2b[(sy << 9) + sx];
        }
    }
    __syncthreads();

    // ---- compute: 2 px/thread/iter, 4 iters. Lanes 0-31 = one row. ----
    int lx = tid & 31;
    int g  = tid >> 5;                   // row group 0..7
    int x  = tx0 + (lx << 1);            // even x in [tx0, tx0+62]

#pragma unroll
    for (int j = 0; j < 4; ++j) {
        int y   = ty0 + g + (j << 3);
        int pix = (y << 9) + x;

        f32x4 fA = __builtin_nontemporal_load(
            reinterpret_cast<const f32x4*>(flow + 2 * (base + pix)));
        f32x2 i1v = *reinterpret_cast<const f32x2*>(I1b + pix);
        float i1n = (x < 510) ? I1b[pix + 2] : 0.0f;
        f32x2 i1d = (y < 511) ? *reinterpret_cast<const f32x2*>(I1b + pix + 512)
                              : i1v;

        float i1a[2]  = { i1v.x, i1v.y };
        float i1ra[2] = { i1v.y, i1n  };
        float i1ba[2] = { i1d.x, i1d.y };
        float ua[2]   = { fA.x, fA.z };
        float va[2]   = { fA.y, fA.w };
        float un[2], vn[2];

#pragma unroll
        for (int k = 0; k < 2; ++k) {
            int xk = x + k;
            float u = ua[k], v = va[k];
            // reference naming swap: "grad_x" = vertical diff, "grad_y" = horizontal
            float g_dy = i1ba[k] - i1a[k];
            float g_dx = (xk < 511) ? (i1ra[k] - i1a[k]) : 0.0f;

            float xx = fminf(fmaxf((float)xk + u, 0.0f), 511.0f);
            float yy = fminf(fmaxf((float)y  + v, 0.0f), 511.0f);
            float x0f = floorf(xx);
            float y0f = floorf(yy);
            int x0 = (int)x0f;
            int y0 = (int)y0f;
            float wx = xx - x0f;
            float wy = yy - y0f;

            float Ia, Ib_, Ic, Id;
            bool oob = fmaxf(fabsf(u), fabsf(v)) > 8.0f;
            if (__builtin_expect(!oob, 1)) {
                int lidx = (y0 - ty0 + 8) * RW + (x0 - tx0 + 8);
                Ia  = s_i2[lidx];
                Ib_ = s_i2[lidx + 1];
                Ic  = s_i2[lidx + RW];
                Id  = s_i2[lidx + RW + 1];
            } else {
                int x1 = min(x0 + 1, 511);
                int y1 = min(y0 + 1, 511);
                Ia  = I2b[(y0 << 9) + x0];
                Ib_ = I2b[(y0 << 9) + x1];
                Ic  = I2b[(y1 << 9) + x0];
                Id  = I2b[(y1 << 9) + x1];
            }

            float top = Ia + wx * (Ib_ - Ia);
            float bot = Ic + wx * (Id - Ic);
            float warped = top + wy * (bot - top);

            float dt = warped - i1a[k];
            un[k] = u - ALPHA * dt * g_dy;
            vn[k] = v - ALPHA * dt * g_dx;
        }

        f32x4 ov;
        ov.x = un[0]; ov.y = vn[0]; ov.z = un[1]; ov.w = vn[1];
        __builtin_nontemporal_store(ov,
            reinterpret_cast<f32x4*>(out + 2 * (base + pix)));
    }
}

extern "C" void kernel_launch(void* const* d_in, const int* in_sizes, int n_in,
                              void* d_out, int out_size, void* d_ws, size_t ws_size,
                              hipStream_t stream) {
    const float* I1   = (const float*)d_in[0];
    const float* I2   = (const float*)d_in[1];
    const float* flow = (const float*)d_in[2];
    float* out = (float*)d_out;

    // 32 images x (8 x-tiles) x (16 y-tiles) = 4096 blocks
    dataterm_kernel<<<4096, 256, 0, stream>>>(I1, I2, flow, out);
}

// Round 7
// 43.315 us; speedup vs baseline: 1.4361x; 1.0035x over previous
//
#include <hip/hip_runtime.h>

#define ALPHA 0.05f

typedef float f32x4 __attribute__((ext_vector_type(4)));
typedef float f32x2 __attribute__((ext_vector_type(2)));

// Tile 64 wide x 32 tall, halo 8 (+1 for x1/y1 tap). Staged I2 region:
// 84 cols x 49 rows = 21 f32x4-chunks/row -> chunk i lives at LDS float
// offset 4*i (rows contiguous). 5 full passes of 256 chunks stage it via
// global_load_lds (linear LDS dest = wave base + lane*16).
constexpr int RW = 84, RH = 49;
constexpr int CH = 21;                  // f32x4 chunks per row
constexpr int NCHUNK = CH * RH;         // 1029
constexpr int LDS_FLOATS = 5 * 256 * 4; // 5120 (passes 4's tail is harmless dup work)

__global__ __launch_bounds__(256) void dataterm_kernel(
    const float* __restrict__ I1,
    const float* __restrict__ I2,
    const float* __restrict__ flow,
    float* __restrict__ out)
{
    __shared__ float s_i2[LDS_FLOATS];

    int blk = blockIdx.x;
    int tx0 = (blk & 7) << 6;            // 8 x-tiles
    int ty0 = ((blk >> 3) & 15) << 5;    // 16 y-tiles
    int b   = blk >> 7;                  // 32 images
    int base = b << 18;

    const float* I2b = I2 + base;
    const float* I1b = I1 + base;
    int tid = threadIdx.x;

    // ---- thread geometry: 32 x-lanes (2 px each) x 4 consecutive rows ----
    int lx = tid & 31;
    int rg = tid >> 5;                   // row group 0..7
    int x  = tx0 + (lx << 1);            // even x
    int yb = ty0 + (rg << 2);            // first of this thread's 4 rows
    int pix0 = (yb << 9) + x;

    // ---- prefetch flow + I1 into registers (latency hides under staging) ----
    f32x4 fA[4];
    f32x2 rowv[5];
    float i1n[4];
#pragma unroll
    for (int j = 0; j < 4; ++j)
        fA[j] = __builtin_nontemporal_load(
            reinterpret_cast<const f32x4*>(flow + 2 * (base + pix0 + (j << 9))));
#pragma unroll
    for (int j = 0; j < 4; ++j)
        rowv[j] = *reinterpret_cast<const f32x2*>(I1b + pix0 + (j << 9));
    // 5th row: only OOB when yb+3 == 511; reuse -> dy row 511 = 0 exactly
    rowv[4] = (yb + 4 < 512)
        ? *reinterpret_cast<const f32x2*>(I1b + pix0 + (4 << 9)) : rowv[3];
#pragma unroll
    for (int j = 0; j < 4; ++j)
        i1n[j] = (x < 510) ? I1b[pix0 + (j << 9) + 2] : 0.0f;

    // ---- stage I2 region: async global->LDS, clamped per-lane source ----
    // Chunk c4 of row r maps to x = tx0-8+c4; clamp source to [0,508] keeps
    // loads in-bounds. Clamped (duplicated) cells are either never read or
    // read only by weight-0 taps (reference clamps coords before floor).
    int wave = tid >> 6;
    int lane = tid & 63;
#pragma unroll
    for (int p = 0; p < 5; ++p) {
        int cb = (p << 8) + (wave << 6);          // wave-uniform chunk base
        int i  = cb + lane;
        int r  = i / 21;
        int c4 = (i - r * 21) << 2;
        int sy = min(max(ty0 - 8 + r, 0), 511);
        int gx = min(max(tx0 - 8 + c4, 0), 508);
        const float* g = I2b + (sy << 9) + gx;
        __builtin_amdgcn_global_load_lds(
            (const __attribute__((address_space(1))) void*)g,
            (__attribute__((address_space(3))) void*)(s_i2 + (cb << 2)),
            16, 0, 0);
    }
    __syncthreads();

    // ---- compute: 2 px x 4 rows per thread, all inputs in regs/LDS ----
#pragma unroll
    for (int j = 0; j < 4; ++j) {
        int y   = yb + j;
        int pix = pix0 + (j << 9);

        float ua[2] = { fA[j].x, fA[j].z };
        float va[2] = { fA[j].y, fA[j].w };
        float i1a[2]  = { rowv[j].x, rowv[j].y };
        float i1ra[2] = { rowv[j].y, i1n[j] };
        float i1ba[2] = { rowv[j + 1].x, rowv[j + 1].y };
        float un[2], vn[2];

#pragma unroll
        for (int k = 0; k < 2; ++k) {
            int xk = x + k;
            float u = ua[k], v = va[k];
            // reference naming swap: "grad_x" = vertical diff, "grad_y" = horizontal
            float g_dy = i1ba[k] - i1a[k];            // rowv[4]==rowv[3] at y==511
            float g_dx = (xk < 511) ? (i1ra[k] - i1a[k]) : 0.0f;

            float xx = fminf(fmaxf((float)xk + u, 0.0f), 511.0f);
            float yy = fminf(fmaxf((float)y  + v, 0.0f), 511.0f);
            float x0f = floorf(xx);
            float y0f = floorf(yy);
            int x0 = (int)x0f;
            int y0 = (int)y0f;
            float wx = xx - x0f;
            float wy = yy - y0f;

            float Ia, Ib_, Ic, Id;
            bool oob = fmaxf(fabsf(u), fabsf(v)) > 8.0f;
            if (__builtin_expect(!oob, 1)) {
                int lidx = (y0 - ty0 + 8) * RW + (x0 - tx0 + 8);
                Ia  = s_i2[lidx];
                Ib_ = s_i2[lidx + 1];
                Ic  = s_i2[lidx + RW];
                Id  = s_i2[lidx + RW + 1];
            } else {
                int x1 = min(x0 + 1, 511);
                int y1 = min(y0 + 1, 511);
                Ia  = I2b[(y0 << 9) + x0];
                Ib_ = I2b[(y0 << 9) + x1];
                Ic  = I2b[(y1 << 9) + x0];
                Id  = I2b[(y1 << 9) + x1];
            }

            float top = Ia + wx * (Ib_ - Ia);
            float bot = Ic + wx * (Id - Ic);
            float warped = top + wy * (bot - top);

            float dt = warped - i1a[k];
            un[k] = u - ALPHA * dt * g_dy;
            vn[k] = v - ALPHA * dt * g_dx;
        }

        f32x4 ov;
        ov.x = un[0]; ov.y = vn[0]; ov.z = un[1]; ov.w = vn[1];
        __builtin_nontemporal_store(ov,
            reinterpret_cast<f32x4*>(out + 2 * (base + pix)));
    }
}

extern "C" void kernel_launch(void* const* d_in, const int* in_sizes, int n_in,
                              void* d_out, int out_size, void* d_ws, size_t ws_size,
                              hipStream_t stream) {
    const float* I1   = (const float*)d_in[0];
    const float* I2   = (const float*)d_in[1];
    const float* flow = (const float*)d_in[2];
    float* out = (float*)d_out;

    // 32 images x (8 x-tiles) x (16 y-tiles) = 4096 blocks
    dataterm_kernel<<<4096, 256, 0, stream>>>(I1, I2, flow, out);
}

// Round 8
// 39.721 us; speedup vs baseline: 1.5660x; 1.0905x over previous
//
#include <hip/hip_runtime.h>

#define ALPHA 0.05f

typedef float f32x4 __attribute__((ext_vector_type(4)));
typedef float f32x2 __attribute__((ext_vector_type(2)));

// Tile 64 wide x 32 tall, halo 8 (+1 for x1/y1 tap). Staged I2 region:
// 84 cols x 49 rows = 21 f32x4-chunks/row, staged via global_load_lds
// (linear LDS dest = wave base + lane*16), clamped per-lane source.
constexpr int RW = 84, RH = 49;
constexpr int LDS_FLOATS = 5 * 256 * 4; // 5120 (pass 4 tail = harmless dup work)

__global__ __launch_bounds__(256) void dataterm_kernel(
    const float* __restrict__ I1,
    const float* __restrict__ I2,
    const float* __restrict__ flow,
    float* __restrict__ out)
{
    __shared__ float s_i2[LDS_FLOATS];

    int blk = blockIdx.x;
    int tx0 = (blk & 7) << 6;            // 8 x-tiles
    int ty0 = ((blk >> 3) & 15) << 5;    // 16 y-tiles
    int b   = blk >> 7;                  // 32 images
    int base = b << 18;

    const float* I2b = I2 + base;
    const float* I1b = I1 + base;
    int tid = threadIdx.x;

    // ---- thread geometry: 32 x-lanes (2 px each) x 4 consecutive rows ----
    int lx = tid & 31;
    int rg = tid >> 5;                   // row group 0..7
    int x  = tx0 + (lx << 1);            // even x
    int yb = ty0 + (rg << 2);            // first of this thread's 4 rows
    int pix0 = (yb << 9) + x;

    // ---- prefetch flow + I1 into registers (latency hides under staging) ----
    // flow is a PLAIN load (allocates in L2/L3 -> L3-resident across replays).
    f32x4 fA[4];
    f32x2 rowv[5];
    float i1n[4];
#pragma unroll
    for (int j = 0; j < 4; ++j)
        fA[j] = *reinterpret_cast<const f32x4*>(flow + 2 * (base + pix0 + (j << 9)));
#pragma unroll
    for (int j = 0; j < 4; ++j)
        rowv[j] = *reinterpret_cast<const f32x2*>(I1b + pix0 + (j << 9));
    // 5th row: only OOB when yb+3 == 511; reuse -> dy row 511 = 0 exactly
    rowv[4] = (yb + 4 < 512)
        ? *reinterpret_cast<const f32x2*>(I1b + pix0 + (4 << 9)) : rowv[3];
#pragma unroll
    for (int j = 0; j < 4; ++j)
        i1n[j] = (x < 510) ? I1b[pix0 + (j << 9) + 2] : 0.0f;

    // ---- stage I2 region: async global->LDS, clamped per-lane source ----
    // Clamped (duplicated) cells are either never read or read only by
    // weight-0 taps (reference clamps coords before floor).
    int wave = tid >> 6;
    int lane = tid & 63;
#pragma unroll
    for (int p = 0; p < 5; ++p) {
        int cb = (p << 8) + (wave << 6);          // wave-uniform chunk base
        int i  = cb + lane;
        int r  = i / 21;
        int c4 = (i - r * 21) << 2;
        int sy = min(max(ty0 - 8 + r, 0), 511);
        int gx = min(max(tx0 - 8 + c4, 0), 508);
        const float* g = I2b + (sy << 9) + gx;
        __builtin_amdgcn_global_load_lds(
            (const __attribute__((address_space(1))) void*)g,
            (__attribute__((address_space(3))) void*)(s_i2 + (cb << 2)),
            16, 0, 0);
    }
    __syncthreads();

    // ---- compute: 2 px x 4 rows per thread, all inputs in regs/LDS ----
#pragma unroll
    for (int j = 0; j < 4; ++j) {
        int y   = yb + j;
        int pix = pix0 + (j << 9);

        float ua[2] = { fA[j].x, fA[j].z };
        float va[2] = { fA[j].y, fA[j].w };
        float i1a[2]  = { rowv[j].x, rowv[j].y };
        float i1ra[2] = { rowv[j].y, i1n[j] };
        float i1ba[2] = { rowv[j + 1].x, rowv[j + 1].y };
        float un[2], vn[2];

#pragma unroll
        for (int k = 0; k < 2; ++k) {
            int xk = x + k;
            float u = ua[k], v = va[k];
            // reference naming swap: "grad_x" = vertical diff, "grad_y" = horizontal
            float g_dy = i1ba[k] - i1a[k];            // rowv[4]==rowv[3] at y==511
            float g_dx = (xk < 511) ? (i1ra[k] - i1a[k]) : 0.0f;

            float xx = fminf(fmaxf((float)xk + u, 0.0f), 511.0f);
            float yy = fminf(fmaxf((float)y  + v, 0.0f), 511.0f);
            float x0f = floorf(xx);
            float y0f = floorf(yy);
            int x0 = (int)x0f;
            int y0 = (int)y0f;
            float wx = xx - x0f;
            float wy = yy - y0f;

            float Ia, Ib_, Ic, Id;
            bool oob = fmaxf(fabsf(u), fabsf(v)) > 8.0f;
            if (__builtin_expect(!oob, 1)) {
                int lidx = (y0 - ty0 + 8) * RW + (x0 - tx0 + 8);
                Ia  = s_i2[lidx];
                Ib_ = s_i2[lidx + 1];
                Ic  = s_i2[lidx + RW];
                Id  = s_i2[lidx + RW + 1];
            } else {
                int x1 = min(x0 + 1, 511);
                int y1 = min(y0 + 1, 511);
                Ia  = I2b[(y0 << 9) + x0];
                Ib_ = I2b[(y0 << 9) + x1];
                Ic  = I2b[(y1 << 9) + x0];
                Id  = I2b[(y1 << 9) + x1];
            }

            float top = Ia + wx * (Ib_ - Ia);
            float bot = Ic + wx * (Id - Ic);
            float warped = top + wy * (bot - top);

            float dt = warped - i1a[k];
            un[k] = u - ALPHA * dt * g_dy;
            vn[k] = v - ALPHA * dt * g_dx;
        }

        f32x4 ov;
        ov.x = un[0]; ov.y = vn[0]; ov.z = un[1]; ov.w = vn[1];
        __builtin_nontemporal_store(ov,
            reinterpret_cast<f32x4*>(out + 2 * (base + pix)));
    }
}

extern "C" void kernel_launch(void* const* d_in, const int* in_sizes, int n_in,
                              void* d_out, int out_size, void* d_ws, size_t ws_size,
                              hipStream_t stream) {
    const float* I1   = (const float*)d_in[0];
    const float* I2   = (const float*)d_in[1];
    const float* flow = (const float*)d_in[2];
    float* out = (float*)d_out;

    // 32 images x (8 x-tiles) x (16 y-tiles) = 4096 blocks
    dataterm_kernel<<<4096, 256, 0, stream>>>(I1, I2, flow, out);
}